// Round 1
// baseline (545.789 us; speedup 1.0000x reference)
//
#include <hip/hip_runtime.h>
#include <hip/hip_bf16.h>

#define N_BAG 500000
#define DIM   128
#define ROWS_PER_ITER 64
#define ITERS 16
#define ROWS_PER_BLOCK 1024          // ROWS_PER_ITER * ITERS
#define NBLK  489                    // ceil(500000/1024)
#define MDIM  256
#define GDIM  64

typedef __attribute__((ext_vector_type(8))) __bf16 bf16x8;
typedef __attribute__((ext_vector_type(4))) float  f32x4;

union BF8 { bf16x8 v; __bf16 e[8]; };

__device__ __forceinline__ float fast_rcp(float x) { return __builtin_amdgcn_rcpf(x); }

// ---------------------------------------------------------------------------
// Pass 1: per 1024-row block: a_i = (tanh(x·Wv)·sigm(x·Wu))·Ww (bf16 MFMA),
// online-softmax partials m_b, s_b, w_b[128] = sum e^{a_i-m_b} x_i.
// Raw a_i written to aOut (= d_out+1), partials to ws.
// ---------------------------------------------------------------------------
__global__ __launch_bounds__(256, 2)
void attn_pass1(const float* __restrict__ bag,
                const float* __restrict__ Wv, const float* __restrict__ bv,
                const float* __restrict__ Wu, const float* __restrict__ bu,
                const float* __restrict__ Ww, const float* __restrict__ bw,
                float* __restrict__ aOut,
                float* __restrict__ blkM, float* __restrict__ blkS,
                float* __restrict__ blkW)
{
    __shared__ bf16x8 Xs[1024];          // 16 KB, MFMA-fragment-ordered tile
    __shared__ float a_part[4][64];
    __shared__ float e_tile[64];
    __shared__ float w_part[2][128];
    __shared__ float m_sh, s_sh, scale_sh;

    const int tid = threadIdx.x;
    const int w   = tid >> 6;            // wave 0..3 (owns h-cols [w*32, w*32+32))
    const int L   = tid & 63;
    const int m16 = L & 15;
    const int q   = L >> 4;
    const int blk = blockIdx.x;
    const int rowBase = blk * ROWS_PER_BLOCK;

    if (tid == 0) { m_sh = -1e30f; s_sh = 0.0f; }
    if (tid < 128) { w_part[0][tid] = 0.0f; w_part[1][tid] = 0.0f; }

    // ---- preload weight B-fragments into registers (once per block) ----
    // B[k=d][n=h]: lane holds h = w*32+ht*16+m16, d = s*32+q*8+j  (W row-major [H,D])
    BF8 fv[2][4], fu[2][4];
    float bvv[2], buu[2], www[2];
#pragma unroll
    for (int ht = 0; ht < 2; ++ht) {
        const int h = w*32 + ht*16 + m16;
        bvv[ht] = bv[h]; buu[ht] = bu[h]; www[ht] = Ww[h];
#pragma unroll
        for (int s = 0; s < 4; ++s) {
            const int d0 = s*32 + q*8;
            const float4 v0 = *(const float4*)(Wv + h*DIM + d0);
            const float4 v1 = *(const float4*)(Wv + h*DIM + d0 + 4);
            const float4 u0 = *(const float4*)(Wu + h*DIM + d0);
            const float4 u1 = *(const float4*)(Wu + h*DIM + d0 + 4);
            fv[ht][s].e[0]=(__bf16)v0.x; fv[ht][s].e[1]=(__bf16)v0.y;
            fv[ht][s].e[2]=(__bf16)v0.z; fv[ht][s].e[3]=(__bf16)v0.w;
            fv[ht][s].e[4]=(__bf16)v1.x; fv[ht][s].e[5]=(__bf16)v1.y;
            fv[ht][s].e[6]=(__bf16)v1.z; fv[ht][s].e[7]=(__bf16)v1.w;
            fu[ht][s].e[0]=(__bf16)u0.x; fu[ht][s].e[1]=(__bf16)u0.y;
            fu[ht][s].e[2]=(__bf16)u0.z; fu[ht][s].e[3]=(__bf16)u0.w;
            fu[ht][s].e[4]=(__bf16)u1.x; fu[ht][s].e[5]=(__bf16)u1.y;
            fu[ht][s].e[6]=(__bf16)u1.z; fu[ht][s].e[7]=(__bf16)u1.w;
        }
    }
    const float bw0 = bw[0];

    // staging regs: thread t owns frag-chunks (r=c, s=w, lane=L), c=0..3
    float4 stg[4][2];
    const int d0 = w*32 + q*8;
#pragma unroll
    for (int c = 0; c < 4; ++c) {
        int grow = rowBase + c*16 + m16;
        if (grow >= N_BAG) grow = N_BAG - 1;
        const float* p = bag + grow*DIM + d0;
        stg[c][0] = *(const float4*)p;
        stg[c][1] = *(const float4*)(p + 4);
    }
    __syncthreads();   // init visible

    for (int it = 0; it < ITERS; ++it) {
        // --- write staged tile to LDS (fragment order), prefetch next tile ---
#pragma unroll
        for (int c = 0; c < 4; ++c) {
            BF8 b;
            b.e[0]=(__bf16)stg[c][0].x; b.e[1]=(__bf16)stg[c][0].y;
            b.e[2]=(__bf16)stg[c][0].z; b.e[3]=(__bf16)stg[c][0].w;
            b.e[4]=(__bf16)stg[c][1].x; b.e[5]=(__bf16)stg[c][1].y;
            b.e[6]=(__bf16)stg[c][1].z; b.e[7]=(__bf16)stg[c][1].w;
            Xs[(c*4 + w)*64 + L] = b.v;
        }
        if (it + 1 < ITERS) {
#pragma unroll
            for (int c = 0; c < 4; ++c) {
                int grow = rowBase + (it+1)*ROWS_PER_ITER + c*16 + m16;
                if (grow >= N_BAG) grow = N_BAG - 1;
                const float* p = bag + grow*DIM + d0;
                stg[c][0] = *(const float4*)p;
                stg[c][1] = *(const float4*)(p + 4);
            }
        }
        __syncthreads();   // Xs ready; prefetch in flight through compute

        // --- MFMA: wave w computes V,U for all 64 rows, h-cols [w*32,w*32+32) ---
#pragma unroll
        for (int r = 0; r < 4; ++r) {
            bf16x8 af[4];
#pragma unroll
            for (int s = 0; s < 4; ++s) af[s] = Xs[(r*4 + s)*64 + L];
            f32x4 accV[2], accU[2];
#pragma unroll
            for (int ht = 0; ht < 2; ++ht) {
                accV[ht] = (f32x4){0.f,0.f,0.f,0.f};
                accU[ht] = (f32x4){0.f,0.f,0.f,0.f};
            }
#pragma unroll
            for (int s = 0; s < 4; ++s) {
#pragma unroll
                for (int ht = 0; ht < 2; ++ht) {
                    accV[ht] = __builtin_amdgcn_mfma_f32_16x16x32_bf16(af[s], fv[ht][s].v, accV[ht], 0, 0, 0);
                    accU[ht] = __builtin_amdgcn_mfma_f32_16x16x32_bf16(af[s], fu[ht][s].v, accU[ht], 0, 0, 0);
                }
            }
            // epilogue: C/D layout col=lane&15 (=h), row=q*4+g. Partial a over 32 h.
            float psum[4];
#pragma unroll
            for (int g = 0; g < 4; ++g) {
                float p = 0.0f;
#pragma unroll
                for (int ht = 0; ht < 2; ++ht) {
                    const float z = accV[ht][g] + bvv[ht];
                    const float y = accU[ht][g] + buu[ht];
                    const float tv = 2.0f * fast_rcp(1.0f + __expf(-2.0f*z)) - 1.0f; // tanh
                    const float su = fast_rcp(1.0f + __expf(-y));                    // sigmoid
                    p += tv * su * www[ht];
                }
                p += __shfl_xor(p, 1); p += __shfl_xor(p, 2);
                p += __shfl_xor(p, 4); p += __shfl_xor(p, 8);
                psum[g] = p;
            }
            if (m16 == 0) {
#pragma unroll
                for (int g = 0; g < 4; ++g) a_part[w][r*16 + q*4 + g] = psum[g];
            }
        }
        __syncthreads();

        // --- wave 0: combine partial a, write raw logits, online-softmax state ---
        if (w == 0) {
            const int grow = rowBase + it*ROWS_PER_ITER + L;
            float a = a_part[0][L] + a_part[1][L] + a_part[2][L] + a_part[3][L] + bw0;
            if (grow < N_BAG) aOut[grow] = a; else a = -1e30f;
            float mt = a;
            mt = fmaxf(mt, __shfl_xor(mt, 1));  mt = fmaxf(mt, __shfl_xor(mt, 2));
            mt = fmaxf(mt, __shfl_xor(mt, 4));  mt = fmaxf(mt, __shfl_xor(mt, 8));
            mt = fmaxf(mt, __shfl_xor(mt, 16)); mt = fmaxf(mt, __shfl_xor(mt, 32));
            const float mold = m_sh;             // all lanes read before lane0 writes
            const float mnew = fmaxf(mold, mt);
            const float sc   = __expf(mold - mnew);
            const float e    = __expf(a - mnew);
            e_tile[L] = e;
            float es = e;
            es += __shfl_xor(es, 1);  es += __shfl_xor(es, 2);
            es += __shfl_xor(es, 4);  es += __shfl_xor(es, 8);
            es += __shfl_xor(es, 16); es += __shfl_xor(es, 32);
            if (L == 0) { m_sh = mnew; scale_sh = sc; s_sh = s_sh * sc + es; }
        }
        __syncthreads();

        // --- weighted sum update: w[g][c] = w[g][c]*scale + sum_j e_j * x[j][c] ---
        {
            const float sc = scale_sh;
            const int c = tid & 127;
            const int g = tid >> 7;
            const int r0 = rowBase + it*ROWS_PER_ITER + g*32;
            float acc = 0.0f;
#pragma unroll
            for (int j = 0; j < 32; ++j) {
                int grow = r0 + j;
                if (grow >= N_BAG) grow = N_BAG - 1;           // e_j==0 masks it
                acc += e_tile[g*32 + j] * bag[grow*DIM + c];   // L1/L2-hot re-read
            }
            w_part[g][c] = w_part[g][c] * sc + acc;
        }
        // no barrier needed: next-iter writers are all behind the next barriers
    }

    __syncthreads();
    if (tid < 128) blkW[blk*128 + tid] = w_part[0][tid] + w_part[1][tid];
    if (tid == 0) { blkM[blk] = m_sh; blkS[blk] = s_sh; }
}

// ---------------------------------------------------------------------------
// Head: reduce block partials -> M, S, embedding; MLP 192->256->1 -> score.
// ---------------------------------------------------------------------------
__global__ void head_kernel(const float* __restrict__ blkM, const float* __restrict__ blkS,
                            const float* __restrict__ blkW, const float* __restrict__ gfeat,
                            const float* __restrict__ W1, const float* __restrict__ b1,
                            const float* __restrict__ W2, const float* __restrict__ b2,
                            float* __restrict__ out, float* __restrict__ ms)
{
    __shared__ float red[256];
    __shared__ float f[192];
    __shared__ float h[256];
    const int tid = threadIdx.x;

    // global max M
    float lm = -1e30f;
    for (int b = tid; b < NBLK; b += 256) lm = fmaxf(lm, blkM[b]);
    red[tid] = lm; __syncthreads();
    for (int s = 128; s > 0; s >>= 1) {
        if (tid < s) red[tid] = fmaxf(red[tid], red[tid + s]);
        __syncthreads();
    }
    const float M = red[0]; __syncthreads();

    // S = sum s_b * e^{m_b - M}
    float ls = 0.0f;
    for (int b = tid; b < NBLK; b += 256) ls += blkS[b] * __expf(blkM[b] - M);
    red[tid] = ls; __syncthreads();
    for (int s = 128; s > 0; s >>= 1) {
        if (tid < s) red[tid] += red[tid + s];
        __syncthreads();
    }
    const float S = red[0]; __syncthreads();

    // E[c] = sum_b w_b[c] * e^{m_b - M}; embedding = E/S
    const int c = tid & 127, g = tid >> 7;
    float E = 0.0f;
    for (int b = g; b < NBLK; b += 2) E += blkW[b*128 + c] * __expf(blkM[b] - M);
    red[g*128 + c] = E; __syncthreads();
    if (tid < 128) f[tid] = (red[tid] + red[128 + tid]) / S;
    if (tid >= 128 && tid < 128 + GDIM) f[tid] = gfeat[tid - 128];
    if (tid == 0) { ms[0] = M; ms[1] = 1.0f / S; }
    __syncthreads();

    // h = leaky_relu(fused @ W1^T + b1)
    float acc = b1[tid];
    const float4* w1p = (const float4*)(W1 + tid * (DIM + GDIM));
    const float4* fp  = (const float4*)f;
#pragma unroll 4
    for (int k = 0; k < (DIM + GDIM) / 4; ++k) {
        const float4 a4 = w1p[k]; const float4 f4 = fp[k];
        acc += a4.x*f4.x + a4.y*f4.y + a4.z*f4.z + a4.w*f4.w;
    }
    h[tid] = acc > 0.0f ? acc : 0.01f * acc;
    __syncthreads();

    // score = h @ W2^T + b2
    red[tid] = h[tid] * W2[tid]; __syncthreads();
    for (int s = 128; s > 0; s >>= 1) {
        if (tid < s) red[tid] += red[tid + s];
        __syncthreads();
    }
    if (tid == 0) out[0] = red[0] + b2[0];
}

// ---------------------------------------------------------------------------
// alpha_i = e^{a_i - M} / S, in-place over the raw logits in d_out[1..N]
// ---------------------------------------------------------------------------
__global__ void alpha_kernel(float* __restrict__ alpha, const float* __restrict__ ms)
{
    const int i = blockIdx.x * blockDim.x + threadIdx.x;
    const float M = ms[0], invS = ms[1];
    if (i < N_BAG) alpha[i] = __expf(alpha[i] - M) * invS;
}

extern "C" void kernel_launch(void* const* d_in, const int* in_sizes, int n_in,
                              void* d_out, int out_size, void* d_ws, size_t ws_size,
                              hipStream_t stream)
{
    const float* bag   = (const float*)d_in[0];
    const float* gfeat = (const float*)d_in[1];
    const float* Wv    = (const float*)d_in[2];
    const float* bv    = (const float*)d_in[3];
    const float* Wu    = (const float*)d_in[4];
    const float* bu    = (const float*)d_in[5];
    const float* Ww    = (const float*)d_in[6];
    const float* bw    = (const float*)d_in[7];
    const float* W1    = (const float*)d_in[8];
    const float* b1    = (const float*)d_in[9];
    const float* W2    = (const float*)d_in[10];
    const float* b2    = (const float*)d_in[11];
    float* out = (float*)d_out;
    float* ws  = (float*)d_ws;

    float* blkM = ws;                    // 489 (pad 512)
    float* blkS = ws + 512;              // 489 (pad 512)
    float* blkW = ws + 1024;             // 489*128 = 62592
    float* msv  = ws + 1024 + 62592;     // 2

    attn_pass1<<<NBLK, 256, 0, stream>>>(bag, Wv, bv, Wu, bu, Ww, bw,
                                         out + 1, blkM, blkS, blkW);
    head_kernel<<<1, 256, 0, stream>>>(blkM, blkS, blkW, gfeat, W1, b1, W2, b2,
                                       out, msv);
    alpha_kernel<<<(N_BAG + 255) / 256, 256, 0, stream>>>(out + 1, msv);
}

// Round 2
// 431.066 us; speedup vs baseline: 1.2661x; 1.2661x over previous
//
#include <hip/hip_runtime.h>
#include <hip/hip_bf16.h>

#define N_BAG 500000
#define DIM   128
#define ROWS_PER_ITER 64
#define ITERS 8
#define ROWS_PER_BLOCK 512           // ROWS_PER_ITER * ITERS
#define NBLK  977                    // ceil(500000/512)
#define GDIM  64
#define LDB   136                    // bf16 row pitch: 272B = 17*16B -> conflict-free b128

typedef __attribute__((ext_vector_type(8))) __bf16 bf16x8;
typedef __attribute__((ext_vector_type(4))) __bf16 bf16x4;
typedef __attribute__((ext_vector_type(4))) float  f32x4;

union BF8 { bf16x8 v; __bf16 e[8]; };

__device__ __forceinline__ float fast_rcp(float x) { return __builtin_amdgcn_rcpf(x); }

// ---------------------------------------------------------------------------
// Pass 1: per 512-row block, 8 iters of 64-row tiles.
// Per iter: [A] regs->LDS bf16 tile  |bar|  [B] prefetch next tile (contiguous
// 1KB/wave bursts) + MFMA a-logits   |bar|  [C/D] per-wave redundant online
// softmax + weighted sum from LDS tile into register accumulators.
// ---------------------------------------------------------------------------
__global__ __launch_bounds__(256, 3)
void attn_pass1(const float* __restrict__ bag,
                const float* __restrict__ Wv, const float* __restrict__ bv,
                const float* __restrict__ Wu, const float* __restrict__ bu,
                const float* __restrict__ Ww, const float* __restrict__ bw,
                float* __restrict__ aOut,
                float* __restrict__ blkM, float* __restrict__ blkS,
                float* __restrict__ blkW)
{
    __shared__ __align__(16) __bf16 Xs[2][ROWS_PER_ITER][LDB];   // 34.8 KB dbuf
    __shared__ float a_part[4][ROWS_PER_ITER];                   // 1 KB
    __shared__ float fin[256][4];                                // 4 KB

    const int tid = threadIdx.x;
    const int w   = tid >> 6;        // wave 0..3 (owns h-cols [w*32, w*32+32))
    const int L   = tid & 63;
    const int m16 = L & 15;
    const int q   = L >> 4;
    const int hh  = L >> 5;          // 0/1 within wave
    const int c32 = L & 31;          // 16B-chunk column (4 fp32 cols)
    const int blk = blockIdx.x;
    const int rowBase = blk * ROWS_PER_BLOCK;

    // ---- weight B-fragments in registers (once per block) ----
    // lane holds h = w*32+ht*16+m16, k = s*32+q*8+j  (W row-major [H,D])
    BF8 fv[2][4], fu[2][4];
    float bvv[2], buu[2], www[2];
#pragma unroll
    for (int ht = 0; ht < 2; ++ht) {
        const int h = w*32 + ht*16 + m16;
        bvv[ht] = bv[h]; buu[ht] = bu[h]; www[ht] = Ww[h];
#pragma unroll
        for (int s = 0; s < 4; ++s) {
            const int d0 = s*32 + q*8;
            const float4 v0 = *(const float4*)(Wv + h*DIM + d0);
            const float4 v1 = *(const float4*)(Wv + h*DIM + d0 + 4);
            const float4 u0 = *(const float4*)(Wu + h*DIM + d0);
            const float4 u1 = *(const float4*)(Wu + h*DIM + d0 + 4);
            fv[ht][s].e[0]=(__bf16)v0.x; fv[ht][s].e[1]=(__bf16)v0.y;
            fv[ht][s].e[2]=(__bf16)v0.z; fv[ht][s].e[3]=(__bf16)v0.w;
            fv[ht][s].e[4]=(__bf16)v1.x; fv[ht][s].e[5]=(__bf16)v1.y;
            fv[ht][s].e[6]=(__bf16)v1.z; fv[ht][s].e[7]=(__bf16)v1.w;
            fu[ht][s].e[0]=(__bf16)u0.x; fu[ht][s].e[1]=(__bf16)u0.y;
            fu[ht][s].e[2]=(__bf16)u0.z; fu[ht][s].e[3]=(__bf16)u0.w;
            fu[ht][s].e[4]=(__bf16)u1.x; fu[ht][s].e[5]=(__bf16)u1.y;
            fu[ht][s].e[6]=(__bf16)u1.z; fu[ht][s].e[7]=(__bf16)u1.w;
        }
    }
    const float bw0 = bw[0];

    // ---- contiguous staging: chunk_id = i*256 + tid; lane L reads base+L*16B
    float4 stg[8];
    {
#pragma unroll
        for (int i = 0; i < 8; ++i) {
            int r = rowBase + i*8 + w*2 + hh;
            if (r >= N_BAG) r = N_BAG - 1;
            stg[i] = *(const float4*)(bag + (size_t)r*DIM + c32*4);
        }
    }

    float m_run = -1e30f, s_run = 0.0f;
    float wacc0 = 0.f, wacc1 = 0.f, wacc2 = 0.f, wacc3 = 0.f;

    for (int it = 0; it < ITERS; ++it) {
        const int buf = it & 1;
        const int tileStart = rowBase + it*ROWS_PER_ITER;

        // --- [A] stg (fp32) -> Xs[buf] (bf16, row-major padded) ---
#pragma unroll
        for (int i = 0; i < 8; ++i) {
            const int row = i*8 + w*2 + hh;
            bf16x4 pk;
            pk.x = (__bf16)stg[i].x; pk.y = (__bf16)stg[i].y;
            pk.z = (__bf16)stg[i].z; pk.w = (__bf16)stg[i].w;
            *(bf16x4*)&Xs[buf][row][c32*4] = pk;
        }
        __syncthreads();   // barrier1: Xs[buf] visible

        // --- [B] prefetch next tile (contiguous bursts), then MFMA ---
        if (it + 1 < ITERS) {
            const int ts2 = tileStart + ROWS_PER_ITER;
#pragma unroll
            for (int i = 0; i < 8; ++i) {
                int r = ts2 + i*8 + w*2 + hh;
                if (r >= N_BAG) r = N_BAG - 1;
                stg[i] = *(const float4*)(bag + (size_t)r*DIM + c32*4);
            }
        }

#pragma unroll
        for (int r = 0; r < 4; ++r) {
            bf16x8 af[4];
#pragma unroll
            for (int s = 0; s < 4; ++s)
                af[s] = *(const bf16x8*)&Xs[buf][r*16 + m16][s*32 + q*8];
            f32x4 accV[2], accU[2];
#pragma unroll
            for (int ht = 0; ht < 2; ++ht) {
                accV[ht] = (f32x4){0.f,0.f,0.f,0.f};
                accU[ht] = (f32x4){0.f,0.f,0.f,0.f};
            }
#pragma unroll
            for (int s = 0; s < 4; ++s) {
#pragma unroll
                for (int ht = 0; ht < 2; ++ht) {
                    accV[ht] = __builtin_amdgcn_mfma_f32_16x16x32_bf16(af[s], fv[ht][s].v, accV[ht], 0, 0, 0);
                    accU[ht] = __builtin_amdgcn_mfma_f32_16x16x32_bf16(af[s], fu[ht][s].v, accU[ht], 0, 0, 0);
                }
            }
            // C/D layout: col=m16 (=h), row=q*4+g. Reduce over wave's 32 h.
            float psum[4];
#pragma unroll
            for (int g = 0; g < 4; ++g) {
                float p = 0.0f;
#pragma unroll
                for (int ht = 0; ht < 2; ++ht) {
                    const float z = accV[ht][g] + bvv[ht];
                    const float y = accU[ht][g] + buu[ht];
                    const float tv = 2.0f * fast_rcp(1.0f + __expf(-2.0f*z)) - 1.0f; // tanh
                    const float su = fast_rcp(1.0f + __expf(-y));                    // sigmoid
                    p += tv * su * www[ht];
                }
                p += __shfl_xor(p, 1); p += __shfl_xor(p, 2);
                p += __shfl_xor(p, 4); p += __shfl_xor(p, 8);
                psum[g] = p;
            }
            if (m16 == 0)
                *(float4*)&a_part[w][r*16 + q*4] = make_float4(psum[0], psum[1], psum[2], psum[3]);
        }
        __syncthreads();   // barrier2: a_part visible; prefetch drained here

        // --- [C/D] redundant per-wave softmax + weighted sum from Xs[buf] ---
        float a = a_part[0][L] + a_part[1][L] + a_part[2][L] + a_part[3][L] + bw0;
        const int grow = tileStart + L;
        if (grow >= N_BAG) a = -1e30f;
        else if (w == 0)   aOut[grow] = a;

        float mt = a;
        mt = fmaxf(mt, __shfl_xor(mt, 1));  mt = fmaxf(mt, __shfl_xor(mt, 2));
        mt = fmaxf(mt, __shfl_xor(mt, 4));  mt = fmaxf(mt, __shfl_xor(mt, 8));
        mt = fmaxf(mt, __shfl_xor(mt, 16)); mt = fmaxf(mt, __shfl_xor(mt, 32));
        const float mnew = fmaxf(m_run, mt);
        const float sc   = __expf(m_run - mnew);
        const float e    = __expf(a - mnew);
        m_run = mnew;
        float es = e;
        es += __shfl_xor(es, 1);  es += __shfl_xor(es, 2);
        es += __shfl_xor(es, 4);  es += __shfl_xor(es, 8);
        es += __shfl_xor(es, 16); es += __shfl_xor(es, 32);
        s_run = s_run * sc + es;

        float s0 = 0.f, s1 = 0.f, s2 = 0.f, s3 = 0.f;
#pragma unroll
        for (int i = 0; i < 8; ++i) {
            const int row = i*8 + w*2 + hh;
            const float ei = __shfl(e, row);
            const bf16x4 xb = *(const bf16x4*)&Xs[buf][row][c32*4];
            s0 += ei * (float)xb.x; s1 += ei * (float)xb.y;
            s2 += ei * (float)xb.z; s3 += ei * (float)xb.w;
        }
        wacc0 = wacc0*sc + s0; wacc1 = wacc1*sc + s1;
        wacc2 = wacc2*sc + s2; wacc3 = wacc3*sc + s3;
        // no barrier: next [A] writes Xs[buf^1]; Xs[buf] rewritten only after
        // the next barrier1, which orders it after these reads.
    }

    fin[tid][0] = wacc0; fin[tid][1] = wacc1;
    fin[tid][2] = wacc2; fin[tid][3] = wacc3;
    __syncthreads();
    if (tid < 128) {
        float v = 0.0f;
#pragma unroll
        for (int k = 0; k < 8; ++k) {                   // w=k>>1, hh=k&1
            const int t = (k >> 1)*64 + (k & 1)*32 + (tid >> 2);
            v += fin[t][tid & 3];
        }
        blkW[blk*DIM + tid] = v;
    }
    if (tid == 0) { blkM[blk] = m_run; blkS[blk] = s_run; }
}

// ---------------------------------------------------------------------------
// Head: 1024 threads. Reduce block partials -> M, S, embedding; MLP -> score.
// ---------------------------------------------------------------------------
__global__ void head_kernel(const float* __restrict__ blkM, const float* __restrict__ blkS,
                            const float* __restrict__ blkW, const float* __restrict__ gfeat,
                            const float* __restrict__ W1, const float* __restrict__ b1,
                            const float* __restrict__ W2, const float* __restrict__ b2,
                            float* __restrict__ out, float* __restrict__ ms)
{
    __shared__ float red[1024];
    __shared__ float scale_s[1024];
    __shared__ float f[192];
    __shared__ float hbuf[256];
    const int tid = threadIdx.x;

    // global max M (NBLK <= 1024: one element per thread)
    red[tid] = (tid < NBLK) ? blkM[tid] : -1e30f;
    __syncthreads();
    for (int s = 512; s > 0; s >>= 1) {
        if (tid < s) red[tid] = fmaxf(red[tid], red[tid + s]);
        __syncthreads();
    }
    const float M = red[0]; __syncthreads();

    // per-block scales + S
    float sc = 0.0f, ls = 0.0f;
    if (tid < NBLK) { sc = __expf(blkM[tid] - M); ls = blkS[tid] * sc; }
    scale_s[tid] = sc;
    red[tid] = ls; __syncthreads();
    for (int s = 512; s > 0; s >>= 1) {
        if (tid < s) red[tid] += red[tid + s];
        __syncthreads();
    }
    const float S = red[0]; __syncthreads();

    // E[c] = sum_b blkW[b][c] * scale[b]
    const int c = tid & 127, g = tid >> 7;   // 8 groups
    float acc = 0.0f;
    for (int b = g; b < NBLK; b += 8) acc += blkW[b*DIM + c] * scale_s[b];
    red[tid] = acc; __syncthreads();
    if (tid < 128) {
        float E = 0.0f;
#pragma unroll
        for (int g2 = 0; g2 < 8; ++g2) E += red[g2*128 + tid];
        f[tid] = E / S;
    }
    if (tid >= 128 && tid < 128 + GDIM) f[tid] = gfeat[tid - 128];
    if (tid == 0) { ms[0] = M; ms[1] = 1.0f / S; }
    __syncthreads();

    // h = leaky_relu(fused @ W1^T + b1)
    if (tid < 256) {
        float a2 = b1[tid];
        const float4* w1p = (const float4*)(W1 + tid * (DIM + GDIM));
        const float4* fp  = (const float4*)f;
#pragma unroll 4
        for (int k = 0; k < (DIM + GDIM) / 4; ++k) {
            const float4 a4 = w1p[k]; const float4 f4 = fp[k];
            a2 += a4.x*f4.x + a4.y*f4.y + a4.z*f4.z + a4.w*f4.w;
        }
        hbuf[tid] = a2 > 0.0f ? a2 : 0.01f * a2;
    }
    __syncthreads();

    red[tid] = (tid < 256) ? hbuf[tid] * W2[tid] : 0.0f;
    __syncthreads();
    for (int s = 512; s > 0; s >>= 1) {
        if (tid < s) red[tid] += red[tid + s];
        __syncthreads();
    }
    if (tid == 0) out[0] = red[0] + b2[0];
}

// ---------------------------------------------------------------------------
// alpha_i = e^{a_i - M} / S, in-place over raw logits in d_out[1..N]
// ---------------------------------------------------------------------------
__global__ void alpha_kernel(float* __restrict__ alpha, const float* __restrict__ ms)
{
    const int i = blockIdx.x * blockDim.x + threadIdx.x;
    const float M = ms[0], invS = ms[1];
    if (i < N_BAG) alpha[i] = __expf(alpha[i] - M) * invS;
}

extern "C" void kernel_launch(void* const* d_in, const int* in_sizes, int n_in,
                              void* d_out, int out_size, void* d_ws, size_t ws_size,
                              hipStream_t stream)
{
    const float* bag   = (const float*)d_in[0];
    const float* gfeat = (const float*)d_in[1];
    const float* Wv    = (const float*)d_in[2];
    const float* bv    = (const float*)d_in[3];
    const float* Wu    = (const float*)d_in[4];
    const float* bu    = (const float*)d_in[5];
    const float* Ww    = (const float*)d_in[6];
    const float* bw    = (const float*)d_in[7];
    const float* W1    = (const float*)d_in[8];
    const float* b1    = (const float*)d_in[9];
    const float* W2    = (const float*)d_in[10];
    const float* b2    = (const float*)d_in[11];
    float* out = (float*)d_out;
    float* ws  = (float*)d_ws;

    float* blkM = ws;                    // 977 (pad 1024)
    float* blkS = ws + 1024;             // 977 (pad 1024)
    float* blkW = ws + 2048;             // 977*128 = 125056
    float* msv  = ws + 2048 + 125056;    // 2

    attn_pass1<<<NBLK, 256, 0, stream>>>(bag, Wv, bv, Wu, bu, Ww, bw,
                                         out + 1, blkM, blkS, blkW);
    head_kernel<<<1, 1024, 0, stream>>>(blkM, blkS, blkW, gfeat, W1, b1, W2, b2,
                                        out, msv);
    alpha_kernel<<<(N_BAG + 255) / 256, 256, 0, stream>>>(out + 1, msv);
}